// Round 17
// baseline (69.041 us; speedup 1.0000x reference)
//
#include <hip/hip_runtime.h>

// QuantizedConv2d: N=32, CIN=128, H=W=56, COUT=256, 3x3, pad=1 (zp=-3), stride 1.
// Round 17: switch to mfma_i32_32x32x32_i8 (32x32 tile). Rationale: conv was
// invariant ~50us across occupancy/LDS-intensity/store/prefetch axes -> cap
// scales per-instruction/per-step. 32x32 halves LDS bytes/op, halves MFMA
// count/op, ~halves addr+wait instructions/op; ceiling 4404 vs 3944 TOPS.
// Block = 256thr/4 waves, 64px x 256couts (wave: 64px x 64cout, acc 2x2x16).
// Halo = 4 padded rows (29.7KB), XOR-swizzled. B global->reg depth-2 ring.
// C/D map (HW-verified m74/m101): cout=lane&31, pixel=(reg&3)+8*(reg>>2)+4*(lane>>5).

typedef __attribute__((ext_vector_type(4))) int i32x4;
typedef __attribute__((ext_vector_type(16))) int i32x16;

#define NB_N 32
#define CIN 128
#define HH 56
#define WW 56
#define PH 58                              // padded H/W
#define COUT 256
#define PIX_PER_IMG (HH*WW)                // 3136
#define X_IMG_INTS (PIX_PER_IMG*CIN)
#define XP_ROW_BYTES (PH*CIN)              // 7424
#define XP_IMG_BYTES (PH*XP_ROW_BYTES)     // 430592
#define XQ_PAD_BYTES ((size_t)NB_N*XP_IMG_BYTES)
#define A4_BYTES (4*XP_ROW_BYTES)          // 29696 (4 halo rows)

// ---------------- pack_x: NCHW int32 -> padded NHWC int8 (+ fused halo) ----------------
#define WPR 33   // words per w-row (132 B)
__global__ __launch_bounds__(256) void pack_x_kernel(const int* __restrict__ x,
                                                     signed char* __restrict__ xq) {
    __shared__ int tile[WW * WPR];           // 7392 B
    int nh = blockIdx.x;                     // 0..N*H-1
    int n = nh / HH, h = nh - n * HH;
    const int* src = x + (size_t)n * X_IMG_INTS + h * WW;  // (n, c, h, 0)
    signed char* img = xq + (size_t)n * XP_IMG_BYTES;
    int q = threadIdx.x & 15;                // w-quad (0..13 valid)
    int cg4 = threadIdx.x >> 4;              // 0..15
    if (q < 14) {
#pragma unroll
        for (int i = 0; i < 2; ++i) {
            int cg = cg4 + i * 16;           // channel group 0..31
            i32x4 v0 = *(const i32x4*)(src + (cg * 4 + 0) * PIX_PER_IMG + q * 4);
            i32x4 v1 = *(const i32x4*)(src + (cg * 4 + 1) * PIX_PER_IMG + q * 4);
            i32x4 v2 = *(const i32x4*)(src + (cg * 4 + 2) * PIX_PER_IMG + q * 4);
            i32x4 v3 = *(const i32x4*)(src + (cg * 4 + 3) * PIX_PER_IMG + q * 4);
#pragma unroll
            for (int j = 0; j < 4; ++j) {
                int word = (v0[j] & 255) | ((v1[j] & 255) << 8) |
                           ((v2[j] & 255) << 16) | (v3[j] << 24);
                tile[(q * 4 + j) * WPR + cg] = word;
            }
        }
    }
    // fused halo (disjoint bytes from interior writes):
    const i32x4 pad = {(int)0xFDFDFDFD, (int)0xFDFDFDFD, (int)0xFDFDFDFD, (int)0xFDFDFDFD};
    {   // side pads of this row (h+1): w=0 and w=57, 128 B each = 8 x 16B
        int t = threadIdx.x;
        if (t < 16) {
            int w = (t >> 3) ? 57 : 0;
            *(i32x4*)(img + ((size_t)(h + 1) * PH + w) * CIN + (t & 7) * 16) = pad;
        }
    }
    if (h == 0) {       // top pad row 0: 7424 B = 464 x 16B
        for (int t = threadIdx.x; t < 464; t += 256)
            *(i32x4*)(img + (size_t)t * 16) = pad;
    }
    if (h == HH - 1) {  // bottom pad row 57
        for (int t = threadIdx.x; t < 464; t += 256)
            *(i32x4*)(img + (size_t)57 * XP_ROW_BYTES + t * 16) = pad;
    }
    __syncthreads();
    int* dst = (int*)(img + ((size_t)(h + 1) * PH + 1) * CIN);
#pragma unroll
    for (int i = 0; i < 7; ++i) {
        int t = i * 256 + threadIdx.x;
        int w = t >> 5, c4 = t & 31;
        dst[w * 32 + c4] = tile[w * WPR + c4];
    }
}

// ---------------- pack_w: OIHW int32 -> 32x32-fragment-ordered int8 ----------------
// frag f = (tap*4 + kblk)*8 + nf; byte = f*1024 + lane*16 + j
// -> weight[cout = nf*32 + (lane&31)][cin = kblk*32 + (lane>>5)*16 + j][kh][kw]
__global__ __launch_bounds__(256) void pack_w_kernel(const int* __restrict__ w,
                                                     signed char* __restrict__ wq) {
    int idx = blockIdx.x * 256 + threadIdx.x;    // 0..18431
    if (idx >= 9 * 4 * 8 * 64) return;
    int lane = idx & 63;
    int fid = idx >> 6;            // 0..287
    int nf = fid & 7;
    int kblk = (fid >> 3) & 3;
    int t = fid >> 5;              // tap 0..8
    int cout = nf * 32 + (lane & 31);
    int cinb = kblk * 32 + (lane >> 5) * 16;
    int kh = t / 3, kw = t - kh * 3;
    union { signed char b[16]; i32x4 v; } u;
#pragma unroll
    for (int j = 0; j < 16; ++j) {
        int cin = cinb + j;
        u.b[j] = (signed char)w[((cout * CIN + cin) * 3 + kh) * 3 + kw];
    }
    *(i32x4*)(wq + (size_t)idx * 16) = u.v;
}

// ---------------- conv: 32x32x32 implicit GEMM, LDS-A + global-reg-B ----------------
// grid = 1568 blocks x 256 thr: img n (32) x pxblock b (49, 64 px each).
// Block covers 64 px x 256 couts. Wave wv: 64 px x couts [wv*64, +64);
// acc[2][2] of i32x16. Halo = 4 padded rows, XOR-swizzled.
__global__ __launch_bounds__(256) void conv_kernel(const signed char* __restrict__ xq,
                                                   const signed char* __restrict__ wq,
                                                   const int* __restrict__ bias,
                                                   const float* __restrict__ wscale,
                                                   int* __restrict__ out) {
    __shared__ __align__(16) signed char lds[A4_BYTES];
    const int tid = threadIdx.x;
    const int lane = tid & 63, wv = tid >> 6;     // wv 0..3
    const int col32 = lane & 31, khalf = lane >> 5;

    // XCD-chunked swizzle: 1568 = 8*196; consecutive 196 blocks (4 images) per XCD.
    int orig = (blockIdx.x & 7) * 196 + (blockIdx.x >> 3);
    int n = orig / 49;
    int b = orig - n * 49;
    const int pb = b * 64;                 // first output pixel of block
    const int r0 = pb / 56;                // first output row touched
    const int cbase = pb - r0 * 56;        // column of first pixel (0,8,...,48)

    const signed char* ximg = xq + (size_t)n * XP_IMG_BYTES + (size_t)r0 * XP_ROW_BYTES;

    // ---- prologue: A-halo (4 padded rows, r0-1..r0+2 in orig coords) ----
    // LDS[d] = global[g],  g = d ^ (((d>>7)&7)<<4)
#pragma unroll
    for (int k = 0; k < 8; ++k) {
        int d = k * 4096 + tid * 16;
        if (d < A4_BYTES) {
            int g = d ^ (((d >> 7) & 7) << 4);
            i32x4 v = *(const i32x4*)(ximg + g);
            *(i32x4*)(lds + d) = v;
        }
    }

    // epilogue constants (hoisted)
    float sc[2];
    int b2[2];
#pragma unroll
    for (int nn = 0; nn < 2; ++nn) {
        int cout = wv * 64 + nn * 32 + col32;
        sc[nn] = wscale[cout] * 0.5f;          // 0.05/0.1 * ws
        b2[nn] = 2 * bias[cout];
    }

    __syncthreads();   // the ONLY barrier

    // per-m center pixel index in halo (padded coords, rows 0..3 of halo)
    int pm[2];
#pragma unroll
    for (int m = 0; m < 2; ++m) {
        int co = cbase + m * 32 + col32;       // 0..111
        int lr = (co >= 56);
        int c = co - lr * 56;
        pm[m] = (lr + 1) * PH + (c + 1);
    }

    const int tapd[9] = {-PH - 1, -PH, -PH + 1, -1, 0, 1, PH - 1, PH, PH + 1};

    // B direct from global (fragment-ordered, L2-resident), depth-2 ring.
    // Wave's 2 n-frags at step stride 8KB; frags nf=2wv, 2wv+1.
    const signed char* wbase = wq + (size_t)(wv * 2) * 1024 + lane * 16;

    i32x16 acc[2][2] = {};
    i32x4 bn[2][2];
    bn[0][0] = *(const i32x4*)(wbase);
    bn[0][1] = *(const i32x4*)(wbase + 1024);
    bn[1][0] = *(const i32x4*)(wbase + 8192);
    bn[1][1] = *(const i32x4*)(wbase + 8192 + 1024);

#pragma unroll
    for (int s = 0; s < 36; ++s) {
        const int t = s >> 2, kblk = s & 3;
        // A ds_reads (swizzled): cin offset = kblk*32 + khalf*16
        i32x4 a[2];
#pragma unroll
        for (int m = 0; m < 2; ++m) {
            int pix = pm[m] + tapd[t];
            int g = (pix << 7) + (kblk << 5) + (khalf << 4);
            int d = g ^ ((pix & 7) << 4);
            a[m] = *(const i32x4*)(lds + d);
        }
        i32x4 b0 = bn[s & 1][0], b1 = bn[s & 1][1];
        acc[0][0] = __builtin_amdgcn_mfma_i32_32x32x32_i8(a[0], b0, acc[0][0], 0, 0, 0);
        acc[0][1] = __builtin_amdgcn_mfma_i32_32x32x32_i8(a[0], b1, acc[0][1], 0, 0, 0);
        acc[1][0] = __builtin_amdgcn_mfma_i32_32x32x32_i8(a[1], b0, acc[1][0], 0, 0, 0);
        acc[1][1] = __builtin_amdgcn_mfma_i32_32x32x32_i8(a[1], b1, acc[1][1], 0, 0, 0);
        if (s < 34) {   // reissue into just-consumed ring slot for step s+2
            bn[s & 1][0] = *(const i32x4*)(wbase + (size_t)(s + 2) * 8192);
            bn[s & 1][1] = *(const i32x4*)(wbase + (size_t)(s + 2) * 8192 + 1024);
        }
    }

    // ---- epilogue: acc + 2*bias -> scale -> rint -> clamp -> int32 store ----
    // D map: cout = nf*32 + (lane&31); pixel = pb + m*32 + (r&3) + 8*(r>>2) + 4*khalf.
    const size_t nbase = (size_t)n * (COUT * PIX_PER_IMG);
#pragma unroll
    for (int m = 0; m < 2; ++m) {
#pragma unroll
        for (int nn = 0; nn < 2; ++nn) {
            int cout = wv * 64 + nn * 32 + col32;
            size_t obase = nbase + (size_t)cout * PIX_PER_IMG + pb + m * 32 + 4 * khalf;
#pragma unroll
            for (int q = 0; q < 4; ++q) {
                i32x4 v;
#pragma unroll
                for (int r = 0; r < 4; ++r) {
                    int o = acc[m][nn][q * 4 + r] + b2[nn];
                    float f = fmaf((float)o, sc[nn], 5.0f);
                    f = rintf(f);                 // RNE == jnp.round
                    f = fminf(fmaxf(f, -128.0f), 127.0f);
                    v[r] = (int)f;
                }
                *(i32x4*)(out + obase + q * 8) = v;
            }
        }
    }
}

extern "C" void kernel_launch(void* const* d_in, const int* in_sizes, int n_in,
                              void* d_out, int out_size, void* d_ws, size_t ws_size,
                              hipStream_t stream) {
    const int* x = (const int*)d_in[0];
    const int* w = (const int*)d_in[1];
    const int* bias = (const int*)d_in[2];
    const float* ws = (const float*)d_in[3];
    int* out = (int*)d_out;

    signed char* xq = (signed char*)d_ws;                 // padded NHWC int8
    signed char* wq = xq + XQ_PAD_BYTES;                  // 288 KB fragment-ordered weights

    pack_x_kernel<<<NB_N * HH, 256, 0, stream>>>(x, xq);  // halo fused in
    pack_w_kernel<<<72, 256, 0, stream>>>(w, wq);
    conv_kernel<<<1568, 256, 0, stream>>>(xq, wq, bias, ws, out);
}

// Round 18
// 66.697 us; speedup vs baseline: 1.0351x; 1.0351x over previous
//
#include <hip/hip_runtime.h>

// QuantizedConv2d: N=32, CIN=128, H=W=56, COUT=256, 3x3, pad=1 (zp=-3), stride 1.
// Round 18: FUSED staging v2. pack_x + xq intermediate eliminated; conv blocks
// transpose their own 4-row NCHW->NHWC-int8 halo into LDS. r13's failure
// causes fixed: (a) all 256 couts per block -> x2 row redundancy (was x4 cout
// redundancy), (b) 1 staging task/thread, 12-16 coalesced-64B int4 loads
// (was 16-deep strided chains), (c) proven word-pack + swizzled b32 writes.
// Host = r16 geometry: 896 x 512thr, 2-row blocks, 8 waves x (112px x 32cout),
// acc[7][2], XOR-swizzled LDS-A, B global->reg depth-1 prefetch, ONE barrier.

typedef __attribute__((ext_vector_type(4))) int i32x4;

#define NB_N 32
#define CIN 128
#define HH 56
#define WW 56
#define PH 58                              // padded row length
#define COUT 256
#define PIX_PER_IMG (HH*WW)                // 3136
#define X_IMG_INTS (PIX_PER_IMG*CIN)
#define XP_ROW_BYTES (PH*CIN)              // 7424
#define A4_BYTES (4*XP_ROW_BYTES)          // 29696 (4 halo rows)

// ---------------- pack_w: OIHW int32 -> fragment-ordered int8 (16x16) ----------------
// frag f = (tap*2 + kb)*16 + nf; byte = f*1024 + lane*16 + j
// -> weight[cout = nf*16 + (lane&15)][cin = kb*64 + (lane>>4)*16 + j][kh][kw]
__global__ __launch_bounds__(256) void pack_w_kernel(const int* __restrict__ w,
                                                     signed char* __restrict__ wq) {
    int idx = blockIdx.x * 256 + threadIdx.x;    // 0..18431
    if (idx >= 9 * 2 * 16 * 64) return;
    int lane = idx & 63;
    int fid = idx >> 6;
    int t = fid / 32;
    int rem = fid - t * 32;
    int kb = rem >> 4;
    int nf = rem & 15;
    int cout = nf * 16 + (lane & 15);
    int cinb = kb * 64 + (lane >> 4) * 16;
    int kh = t / 3, kw = t - kh * 3;
    union { signed char b[16]; i32x4 v; } u;
#pragma unroll
    for (int j = 0; j < 16; ++j) {
        int cin = cinb + j;
        u.b[j] = (signed char)w[((cout * CIN + cin) * 3 + kh) * 3 + kw];
    }
    *(i32x4*)(wq + (size_t)idx * 16) = u.v;
}

// ---------------- conv: fused-staging implicit GEMM (16x16x64 i8) ----------------
// grid = 896 blocks x 512 thr: img n (32) x rowblk rb (28, 2 output rows each).
// Block covers 112 px x 256 couts. Wave wv: 112 px x couts [wv*32,+32); acc[7][2].
// Staging: 512 tasks (row 0..3, cq 0..31, wseg 0..3); each transposes 4 channels
// x ~14 w-positions of one halo row into swizzled LDS words.
__global__ __launch_bounds__(512) void conv_kernel(const int* __restrict__ x,
                                                   const signed char* __restrict__ wq,
                                                   const int* __restrict__ bias,
                                                   const float* __restrict__ wscale,
                                                   int* __restrict__ out) {
    __shared__ __align__(16) signed char lds[A4_BYTES];
    const int tid = threadIdx.x;
    const int lane = tid & 63, wv = tid >> 6;     // wv 0..7
    const int row = lane & 15, grp = lane >> 4;

    // XCD-chunked swizzle: 896 = 8*112; consecutive 112 blocks (4 images) per XCD.
    int orig = (blockIdx.x & 7) * 112 + (blockIdx.x >> 3);
    int n = orig / 28;
    int rb = orig - n * 28;        // 2-row block: output rows [rb*2, rb*2+2)

    // ---- fused staging: NCHW int32 -> swizzled NHWC-int8 4-row halo ----
    // halo pixel pix = srow*58 + px; global h = rb*2-1+srow, w = px-1.
    // LDS word at byte d = (pix*128 + cq*4) ^ ((pix&7)<<4).
    {
        const i32x4 padv = {(int)0xFDFDFDFD, (int)0xFDFDFDFD, (int)0xFDFDFDFD, (int)0xFDFDFDFD};
        int srow = tid >> 7;           // 0..3
        int cq = (tid >> 2) & 31;      // channel quad
        int wseg = tid & 3;
        int h = rb * 2 - 1 + srow;
        if ((unsigned)h < (unsigned)HH) {
            const int* src0 = x + ((size_t)n * CIN + cq * 4) * PIX_PER_IMG + h * WW;
#pragma unroll
            for (int qi = 0; qi < 4; ++qi) {
                int q = wseg + qi * 4;     // w-quad 0..13
                if (q < 14) {
                    i32x4 v0 = *(const i32x4*)(src0 + 0 * PIX_PER_IMG + q * 4);
                    i32x4 v1 = *(const i32x4*)(src0 + 1 * PIX_PER_IMG + q * 4);
                    i32x4 v2 = *(const i32x4*)(src0 + 2 * PIX_PER_IMG + q * 4);
                    i32x4 v3 = *(const i32x4*)(src0 + 3 * PIX_PER_IMG + q * 4);
#pragma unroll
                    for (int j = 0; j < 4; ++j) {
                        int word = (v0[j] & 255) | ((v1[j] & 255) << 8) |
                                   ((v2[j] & 255) << 16) | (v3[j] << 24);
                        int pix = srow * PH + q * 4 + j + 1;
                        int d = ((pix << 7) + cq * 4) ^ ((pix & 7) << 4);
                        *(int*)(lds + d) = word;
                    }
                }
            }
            if (wseg < 2 && cq < 8) {   // side pads px=0 / px=57 (8x16B each)
                int pix = srow * PH + (wseg ? 57 : 0);
                int d = ((pix << 7) + cq * 16) ^ ((pix & 7) << 4);
                *(i32x4*)(lds + d) = padv;
            }
        } else {                        // whole halo row out of range -> pad
            for (int u = (tid & 127); u < 464; u += 128) {
                int g = srow * XP_ROW_BYTES + u * 16;
                int pix = g >> 7;
                int d = g ^ ((pix & 7) << 4);
                *(i32x4*)(lds + d) = padv;
            }
        }
    }

    // epilogue constants hoisted before the K-loop
    float sc[2];
    int b2[2];
    const int coutbase = wv * 32;
#pragma unroll
    for (int j = 0; j < 2; ++j) {
        int cout = coutbase + j * 16 + row;
        sc[j] = wscale[cout] * 0.5f;          // 0.05/0.1 * ws
        b2[j] = 2 * bias[cout];
    }

    __syncthreads();   // the ONLY barrier

    // per-m center pixel index in halo (padded coords, rows 0..3 of halo)
    int pc[7];
#pragma unroll
    for (int m = 0; m < 7; ++m) {
        int off = m * 16 + row;        // 0..111
        int lr = (off >= 56);
        int w = off - lr * 56;
        pc[m] = (lr + 1) * PH + (w + 1);
    }

    const int tapd[9] = {-PH - 1, -PH, -PH + 1, -1, 0, 1, PH - 1, PH, PH + 1};

    // B direct from global (fragment-ordered, L2-resident), 1-step prefetch.
    // Wave's 2 n-frags: nf = wv*2 + {0,1}.  Step stride = 16KB.
    const signed char* wbase = wq + (size_t)(wv * 2) * 1024 + lane * 16;

    i32x4 acc[7][2] = {};
    i32x4 bn0 = *(const i32x4*)(wbase);
    i32x4 bn1 = *(const i32x4*)(wbase + 1024);

#pragma unroll
    for (int s = 0; s < 18; ++s) {
        const int t = s >> 1, kb = s & 1;
        i32x4 b0 = bn0, b1 = bn1;
        if (s < 17) {   // prefetch next step's B fragments (hidden under 14 MFMAs)
            bn0 = *(const i32x4*)(wbase + (s + 1) * 16384);
            bn1 = *(const i32x4*)(wbase + (s + 1) * 16384 + 1024);
        }
        // A ds_reads (swizzled)
        i32x4 a[7];
#pragma unroll
        for (int m = 0; m < 7; ++m) {
            int pix = pc[m] + tapd[t];
            int g = (pix << 7) + (kb << 6) + (grp << 4);
            int d = g ^ ((pix & 7) << 4);
            a[m] = *(const i32x4*)(lds + d);
        }
#pragma unroll
        for (int m = 0; m < 7; ++m) {
            acc[m][0] = __builtin_amdgcn_mfma_i32_16x16x64_i8(a[m], b0, acc[m][0], 0, 0, 0);
            acc[m][1] = __builtin_amdgcn_mfma_i32_16x16x64_i8(a[m], b1, acc[m][1], 0, 0, 0);
        }
    }

    // ---- epilogue: acc + 2*bias -> scale -> rint -> clamp -> int32 store ----
    const int pixbase = rb * 112;
#pragma unroll
    for (int m = 0; m < 7; ++m) {
        int pl = pixbase + m * 16 + grp * 4;  // pixel of reg 0
        size_t obase = (size_t)n * (COUT * PIX_PER_IMG) + pl;
#pragma unroll
        for (int j = 0; j < 2; ++j) {
            int cout = coutbase + j * 16 + row;
            i32x4 v;
#pragma unroll
            for (int r = 0; r < 4; ++r) {
                int o = acc[m][j][r] + b2[j];
                float f = fmaf((float)o, sc[j], 5.0f);
                f = rintf(f);                 // RNE == jnp.round
                f = fminf(fmaxf(f, -128.0f), 127.0f);
                v[r] = (int)f;
            }
            *(i32x4*)(out + obase + (size_t)cout * PIX_PER_IMG) = v;
        }
    }
}

extern "C" void kernel_launch(void* const* d_in, const int* in_sizes, int n_in,
                              void* d_out, int out_size, void* d_ws, size_t ws_size,
                              hipStream_t stream) {
    const int* x = (const int*)d_in[0];
    const int* w = (const int*)d_in[1];
    const int* bias = (const int*)d_in[2];
    const float* ws = (const float*)d_in[3];
    int* out = (int*)d_out;

    signed char* wq = (signed char*)d_ws;      // 288 KB fragment-ordered weights

    pack_w_kernel<<<72, 256, 0, stream>>>(w, wq);
    conv_kernel<<<896, 512, 0, stream>>>(x, wq, bias, ws, out);
}

// Round 19
// 64.457 us; speedup vs baseline: 1.0711x; 1.0348x over previous
//
#include <hip/hip_runtime.h>

// QuantizedConv2d: N=32, CIN=128, H=W=56, COUT=256, 3x3, pad=1 (zp=-3), stride 1.
// Round 19: r15 (measured best, 63.8us) + async A-prologue via
// __builtin_amdgcn_global_load_lds (16B): pre-swizzled per-lane GLOBAL source,
// LINEAR LDS dest, swizzled ds_read (m173/m201 both-sides-or-neither pattern).
// Removes the global->VGPR->LDS round-trip from the per-block serial prologue.
// Core: 1792 x 256thr, (256,3), acc[7][2], XOR-swizzled LDS-A, B global->reg
// depth-1 prefetch, LDS-transposed contiguous-store epilogue.

typedef __attribute__((ext_vector_type(4))) int i32x4;

#define NB_N 32
#define CIN 128
#define HH 56
#define WW 56
#define PH 58                              // padded H/W
#define COUT 256
#define PIX_PER_IMG (HH*WW)                // 3136
#define X_IMG_INTS (PIX_PER_IMG*CIN)
#define XP_ROW_BYTES (PH*CIN)              // 7424
#define XP_IMG_BYTES (PH*XP_ROW_BYTES)     // 430592
#define XQ_PAD_BYTES ((size_t)NB_N*XP_IMG_BYTES)
#define A_BYTES (6*XP_ROW_BYTES)           // 44544
#define EP_STRIDE 228                      // ints per cout row in epilogue LDS (912 B)

// ---------------- pack_x: NCHW int32 -> padded NHWC int8 (+ fused halo) ----------------
#define WPR 33   // words per w-row (132 B)
__global__ __launch_bounds__(256) void pack_x_kernel(const int* __restrict__ x,
                                                     signed char* __restrict__ xq) {
    __shared__ int tile[WW * WPR];           // 7392 B
    int nh = blockIdx.x;                     // 0..N*H-1
    int n = nh / HH, h = nh - n * HH;
    const int* src = x + (size_t)n * X_IMG_INTS + h * WW;  // (n, c, h, 0)
    signed char* img = xq + (size_t)n * XP_IMG_BYTES;
    int q = threadIdx.x & 15;                // w-quad (0..13 valid)
    int cg4 = threadIdx.x >> 4;              // 0..15
    if (q < 14) {
#pragma unroll
        for (int i = 0; i < 2; ++i) {
            int cg = cg4 + i * 16;           // channel group 0..31
            i32x4 v0 = *(const i32x4*)(src + (cg * 4 + 0) * PIX_PER_IMG + q * 4);
            i32x4 v1 = *(const i32x4*)(src + (cg * 4 + 1) * PIX_PER_IMG + q * 4);
            i32x4 v2 = *(const i32x4*)(src + (cg * 4 + 2) * PIX_PER_IMG + q * 4);
            i32x4 v3 = *(const i32x4*)(src + (cg * 4 + 3) * PIX_PER_IMG + q * 4);
#pragma unroll
            for (int j = 0; j < 4; ++j) {
                int word = (v0[j] & 255) | ((v1[j] & 255) << 8) |
                           ((v2[j] & 255) << 16) | (v3[j] << 24);
                tile[(q * 4 + j) * WPR + cg] = word;
            }
        }
    }
    // fused halo (disjoint bytes from interior writes):
    const i32x4 pad = {(int)0xFDFDFDFD, (int)0xFDFDFDFD, (int)0xFDFDFDFD, (int)0xFDFDFDFD};
    {   // side pads of this row (h+1): w=0 and w=57, 128 B each = 8 x 16B
        int t = threadIdx.x;
        if (t < 16) {
            int w = (t >> 3) ? 57 : 0;
            *(i32x4*)(img + ((size_t)(h + 1) * PH + w) * CIN + (t & 7) * 16) = pad;
        }
    }
    if (h == 0) {       // top pad row 0: 7424 B = 464 x 16B
        for (int t = threadIdx.x; t < 464; t += 256)
            *(i32x4*)(img + (size_t)t * 16) = pad;
    }
    if (h == HH - 1) {  // bottom pad row 57
        for (int t = threadIdx.x; t < 464; t += 256)
            *(i32x4*)(img + (size_t)57 * XP_ROW_BYTES + t * 16) = pad;
    }
    __syncthreads();
    int* dst = (int*)(img + ((size_t)(h + 1) * PH + 1) * CIN);
#pragma unroll
    for (int i = 0; i < 7; ++i) {
        int t = i * 256 + threadIdx.x;
        int w = t >> 5, c4 = t & 31;
        dst[w * 32 + c4] = tile[w * WPR + c4];
    }
}

// ---------------- pack_w: OIHW int32 -> fragment-ordered int8 ----------------
// frag f = (tap*2 + kb)*16 + nf; byte = f*1024 + lane*16 + j
// -> weight[cout = nf*16 + (lane&15)][cin = kb*64 + (lane>>4)*16 + j][kh][kw]
__global__ __launch_bounds__(256) void pack_w_kernel(const int* __restrict__ w,
                                                     signed char* __restrict__ wq) {
    int idx = blockIdx.x * 256 + threadIdx.x;    // 0..18431
    if (idx >= 9 * 2 * 16 * 64) return;
    int lane = idx & 63;
    int fid = idx >> 6;
    int t = fid / 32;
    int rem = fid - t * 32;
    int kb = rem >> 4;
    int nf = rem & 15;
    int cout = nf * 16 + (lane & 15);
    int cinb = kb * 64 + (lane >> 4) * 16;
    int kh = t / 3, kw = t - kh * 3;
    union { signed char b[16]; i32x4 v; } u;
#pragma unroll
    for (int j = 0; j < 16; ++j) {
        int cin = cinb + j;
        u.b[j] = (signed char)w[((cout * CIN + cin) * 3 + kh) * 3 + kw];
    }
    *(i32x4*)(wq + (size_t)idx * 16) = u.v;
}

// ---------------- conv: LDS-A + global-reg-B implicit GEMM ----------------
// grid = 1792 blocks: img n (32) x rowblk rb (14, 4 rows) x coutblk cq (4, 64 couts).
// wave (pxhalf, chalf): 112 px (7 m-frags) x 32 couts (2 n-frags); acc[7][2].
__global__ __launch_bounds__(256, 3) void conv_kernel(const signed char* __restrict__ xq,
                                                      const signed char* __restrict__ wq,
                                                      const int* __restrict__ bias,
                                                      const float* __restrict__ wscale,
                                                      int* __restrict__ out) {
    __shared__ __align__(16) signed char lds[A_BYTES];   // A-halo, then epilogue buffer
    const int tid = threadIdx.x;
    const int lane = tid & 63, wv = tid >> 6;
    const int row = lane & 15, grp = lane >> 4;

    // XCD-chunked swizzle: 1792 = 8*224; consecutive 224 blocks (4 images) per XCD.
    int orig = (blockIdx.x & 7) * 224 + (blockIdx.x >> 3);
    int n = orig / 56;
    int rr = orig - n * 56;
    int rb = rr >> 2;          // row-block: output rows [rb*4, rb*4+4)
    int cq = rr & 3;           // cout quarter: [cq*64, +64)
    int pxhalf = wv >> 1, chalf = wv & 1;

    const signed char* ximg = xq + (size_t)n * XP_IMG_BYTES + (size_t)rb * 4 * XP_ROW_BYTES;

    // ---- prologue: async A-halo staging via global_load_lds (16B/lane) ----
    // LDS linear dest d = c*1024 + lane*16; per-lane global src g = d ^ swz(d).
    // ds_reads later apply the same swizzle -> net layout identical to r15.
    for (int c = wv; c < 44; c += 4) {
        int d = c * 1024 + lane * 16;
        if (d < A_BYTES) {
            int g = d ^ (((d >> 7) & 7) << 4);
            __builtin_amdgcn_global_load_lds(
                (const __attribute__((address_space(1))) void*)(ximg + g),
                (__attribute__((address_space(3))) void*)(lds + c * 1024),
                16, 0, 0);
        }
    }

    // epilogue constants hoisted before the K-loop
    float sc[2];
    int b2[2];
    const int coutbase = cq * 64 + chalf * 32;
#pragma unroll
    for (int j = 0; j < 2; ++j) {
        int cout = coutbase + j * 16 + row;
        sc[j] = wscale[cout] * 0.5f;          // 0.05/0.1 * ws
        b2[j] = 2 * bias[cout];
    }

    __syncthreads();   // waits vmcnt(0): staged A visible

    // per-m center pixel index in halo (padded coords, rows 0..5 of halo)
    int pc[7];
#pragma unroll
    for (int m = 0; m < 7; ++m) {
        int off = pxhalf * 112 + m * 16 + row;               // 0..223
        int lr = (off >= 56) + (off >= 112) + (off >= 168);  // off/56
        int w = off - lr * 56;
        pc[m] = (lr + 1) * PH + (w + 1);
    }

    const int tapd[9] = {-PH - 1, -PH, -PH + 1, -1, 0, 1, PH - 1, PH, PH + 1};

    // B direct from global (fragment-ordered, L2-resident), 1-step prefetch.
    const signed char* wbase = wq + (size_t)(cq * 4 + chalf * 2) * 1024 + lane * 16;

    i32x4 acc[7][2] = {};
    i32x4 bn0 = *(const i32x4*)(wbase);
    i32x4 bn1 = *(const i32x4*)(wbase + 1024);

#pragma unroll
    for (int s = 0; s < 18; ++s) {
        const int t = s >> 1, kb = s & 1;
        i32x4 b0 = bn0, b1 = bn1;
        if (s < 17) {   // prefetch next step's B fragments (hidden under 14 MFMAs)
            bn0 = *(const i32x4*)(wbase + (s + 1) * 16384);
            bn1 = *(const i32x4*)(wbase + (s + 1) * 16384 + 1024);
        }
        // A ds_reads (swizzled)
        i32x4 a[7];
#pragma unroll
        for (int m = 0; m < 7; ++m) {
            int pix = pc[m] + tapd[t];
            int g = (pix << 7) + (kb << 6) + (grp << 4);
            int d = g ^ ((pix & 7) << 4);
            a[m] = *(const i32x4*)(lds + d);
        }
#pragma unroll
        for (int m = 0; m < 7; ++m) {
            acc[m][0] = __builtin_amdgcn_mfma_i32_16x16x64_i8(a[m], b0, acc[m][0], 0, 0, 0);
            acc[m][1] = __builtin_amdgcn_mfma_i32_16x16x64_i8(a[m], b1, acc[m][1], 0, 0, 0);
        }
    }

    // ---- epilogue: quantize -> LDS transpose -> contiguous b128 stores ----
    __syncthreads();                     // all waves done with A-LDS
    int* elds = (int*)lds;
    const int pixbase = rb * 224;
    const size_t nbase = (size_t)n * (COUT * PIX_PER_IMG);
#pragma unroll
    for (int p = 0; p < 2; ++p) {
        if (chalf == p) {
#pragma unroll
            for (int m = 0; m < 7; ++m) {
                int px0 = pxhalf * 112 + m * 16 + grp * 4;
#pragma unroll
                for (int j = 0; j < 2; ++j) {
                    int cl = j * 16 + row;
                    i32x4 v;
#pragma unroll
                    for (int r = 0; r < 4; ++r) {
                        int o = acc[m][j][r] + b2[j];
                        float f = fmaf((float)o, sc[j], 5.0f);
                        f = rintf(f);                 // RNE == jnp.round
                        f = fminf(fmaxf(f, -128.0f), 127.0f);
                        v[r] = (int)f;
                    }
                    *(i32x4*)(elds + cl * EP_STRIDE + px0) = v;
                }
            }
        }
        __syncthreads();
        // all 4 waves: read back rows, store contiguous 896B-per-cout runs
#pragma unroll
        for (int rnd = 0; rnd < 7; ++rnd) {
            int tg = rnd * 256 + tid;          // 0..1791 = 32 couts x 56 quads
            int cl = tg / 56;
            int q = tg - cl * 56;
            i32x4 v = *(const i32x4*)(elds + cl * EP_STRIDE + q * 4);
            int cout = cq * 64 + p * 32 + cl;
            *(i32x4*)(out + nbase + (size_t)cout * PIX_PER_IMG + pixbase + q * 4) = v;
        }
        __syncthreads();
    }
}

extern "C" void kernel_launch(void* const* d_in, const int* in_sizes, int n_in,
                              void* d_out, int out_size, void* d_ws, size_t ws_size,
                              hipStream_t stream) {
    const int* x = (const int*)d_in[0];
    const int* w = (const int*)d_in[1];
    const int* bias = (const int*)d_in[2];
    const float* ws = (const float*)d_in[3];
    int* out = (int*)d_out;

    signed char* xq = (signed char*)d_ws;                 // padded NHWC int8
    signed char* wq = xq + XQ_PAD_BYTES;                  // 288 KB fragment-ordered weights

    pack_x_kernel<<<NB_N * HH, 256, 0, stream>>>(x, xq);  // halo fused in
    pack_w_kernel<<<72, 256, 0, stream>>>(w, wq);
    conv_kernel<<<1792, 256, 0, stream>>>(xq, wq, bias, ws, out);
}

// Round 20
// 60.848 us; speedup vs baseline: 1.1346x; 1.0593x over previous
//
#include <hip/hip_runtime.h>

// QuantizedConv2d: N=32, CIN=128, H=W=56, COUT=256, 3x3, pad=1 (zp=-3), stride 1.
// Round 20: r15 (measured best 63.8us) + NONTEMPORAL contiguous epilogue
// stores. Theory: conv invariant ~48-50us across ALL compute axes because the
// 103MB output write drain (~2.1-2.3 TB/s effective through L2, vs 7 TB/s for
// the harness's sequential fill) is the critical path. r15's epilogue already
// writes full 64B lines in 896B-aligned runs -> nt full-line writes bypass L2
// eviction scatter. Everything else = r15 verbatim.

typedef __attribute__((ext_vector_type(4))) int i32x4;

#define NB_N 32
#define CIN 128
#define HH 56
#define WW 56
#define PH 58                              // padded H/W
#define COUT 256
#define PIX_PER_IMG (HH*WW)                // 3136
#define X_IMG_INTS (PIX_PER_IMG*CIN)
#define XP_ROW_BYTES (PH*CIN)              // 7424
#define XP_IMG_BYTES (PH*XP_ROW_BYTES)     // 430592
#define XQ_PAD_BYTES ((size_t)NB_N*XP_IMG_BYTES)
#define A_BYTES (6*XP_ROW_BYTES)           // 44544
#define EP_STRIDE 228                      // ints per cout row in epilogue LDS (912 B)

// ---------------- pack_x: NCHW int32 -> padded NHWC int8 (+ fused halo) ----------------
#define WPR 33   // words per w-row (132 B)
__global__ __launch_bounds__(256) void pack_x_kernel(const int* __restrict__ x,
                                                     signed char* __restrict__ xq) {
    __shared__ int tile[WW * WPR];           // 7392 B
    int nh = blockIdx.x;                     // 0..N*H-1
    int n = nh / HH, h = nh - n * HH;
    const int* src = x + (size_t)n * X_IMG_INTS + h * WW;  // (n, c, h, 0)
    signed char* img = xq + (size_t)n * XP_IMG_BYTES;
    int q = threadIdx.x & 15;                // w-quad (0..13 valid)
    int cg4 = threadIdx.x >> 4;              // 0..15
    if (q < 14) {
#pragma unroll
        for (int i = 0; i < 2; ++i) {
            int cg = cg4 + i * 16;           // channel group 0..31
            i32x4 v0 = *(const i32x4*)(src + (cg * 4 + 0) * PIX_PER_IMG + q * 4);
            i32x4 v1 = *(const i32x4*)(src + (cg * 4 + 1) * PIX_PER_IMG + q * 4);
            i32x4 v2 = *(const i32x4*)(src + (cg * 4 + 2) * PIX_PER_IMG + q * 4);
            i32x4 v3 = *(const i32x4*)(src + (cg * 4 + 3) * PIX_PER_IMG + q * 4);
#pragma unroll
            for (int j = 0; j < 4; ++j) {
                int word = (v0[j] & 255) | ((v1[j] & 255) << 8) |
                           ((v2[j] & 255) << 16) | (v3[j] << 24);
                tile[(q * 4 + j) * WPR + cg] = word;
            }
        }
    }
    // fused halo (disjoint bytes from interior writes):
    const i32x4 pad = {(int)0xFDFDFDFD, (int)0xFDFDFDFD, (int)0xFDFDFDFD, (int)0xFDFDFDFD};
    {   // side pads of this row (h+1): w=0 and w=57, 128 B each = 8 x 16B
        int t = threadIdx.x;
        if (t < 16) {
            int w = (t >> 3) ? 57 : 0;
            *(i32x4*)(img + ((size_t)(h + 1) * PH + w) * CIN + (t & 7) * 16) = pad;
        }
    }
    if (h == 0) {       // top pad row 0: 7424 B = 464 x 16B
        for (int t = threadIdx.x; t < 464; t += 256)
            *(i32x4*)(img + (size_t)t * 16) = pad;
    }
    if (h == HH - 1) {  // bottom pad row 57
        for (int t = threadIdx.x; t < 464; t += 256)
            *(i32x4*)(img + (size_t)57 * XP_ROW_BYTES + t * 16) = pad;
    }
    __syncthreads();
    int* dst = (int*)(img + ((size_t)(h + 1) * PH + 1) * CIN);
#pragma unroll
    for (int i = 0; i < 7; ++i) {
        int t = i * 256 + threadIdx.x;
        int w = t >> 5, c4 = t & 31;
        dst[w * 32 + c4] = tile[w * WPR + c4];
    }
}

// ---------------- pack_w: OIHW int32 -> fragment-ordered int8 ----------------
// frag f = (tap*2 + kb)*16 + nf; byte = f*1024 + lane*16 + j
// -> weight[cout = nf*16 + (lane&15)][cin = kb*64 + (lane>>4)*16 + j][kh][kw]
__global__ __launch_bounds__(256) void pack_w_kernel(const int* __restrict__ w,
                                                     signed char* __restrict__ wq) {
    int idx = blockIdx.x * 256 + threadIdx.x;    // 0..18431
    if (idx >= 9 * 2 * 16 * 64) return;
    int lane = idx & 63;
    int fid = idx >> 6;
    int t = fid / 32;
    int rem = fid - t * 32;
    int kb = rem >> 4;
    int nf = rem & 15;
    int cout = nf * 16 + (lane & 15);
    int cinb = kb * 64 + (lane >> 4) * 16;
    int kh = t / 3, kw = t - kh * 3;
    union { signed char b[16]; i32x4 v; } u;
#pragma unroll
    for (int j = 0; j < 16; ++j) {
        int cin = cinb + j;
        u.b[j] = (signed char)w[((cout * CIN + cin) * 3 + kh) * 3 + kw];
    }
    *(i32x4*)(wq + (size_t)idx * 16) = u.v;
}

// ---------------- conv: LDS-A + global-reg-B implicit GEMM ----------------
// grid = 1792 blocks: img n (32) x rowblk rb (14, 4 rows) x coutblk cq (4, 64 couts).
// wave (pxhalf, chalf): 112 px (7 m-frags) x 32 couts (2 n-frags); acc[7][2].
__global__ __launch_bounds__(256, 3) void conv_kernel(const signed char* __restrict__ xq,
                                                      const signed char* __restrict__ wq,
                                                      const int* __restrict__ bias,
                                                      const float* __restrict__ wscale,
                                                      int* __restrict__ out) {
    __shared__ __align__(16) signed char lds[A_BYTES];   // A-halo, then epilogue buffer
    const int tid = threadIdx.x;
    const int lane = tid & 63, wv = tid >> 6;
    const int row = lane & 15, grp = lane >> 4;

    // XCD-chunked swizzle: 1792 = 8*224; consecutive 224 blocks (4 images) per XCD.
    int orig = (blockIdx.x & 7) * 224 + (blockIdx.x >> 3);
    int n = orig / 56;
    int rr = orig - n * 56;
    int rb = rr >> 2;          // row-block: output rows [rb*4, rb*4+4)
    int cq = rr & 3;           // cout quarter: [cq*64, +64)
    int pxhalf = wv >> 1, chalf = wv & 1;

    const signed char* ximg = xq + (size_t)n * XP_IMG_BYTES + (size_t)rb * 4 * XP_ROW_BYTES;

    // ---- prologue: A-halo (6 padded rows) into LDS, swizzled ----
    // LDS[d] = global[g],  g = d ^ (((d>>7)&7)<<4)   (involution on bits 4-6)
#pragma unroll
    for (int k = 0; k < 11; ++k) {
        int d = k * 4096 + tid * 16;
        if (d < A_BYTES) {
            int g = d ^ (((d >> 7) & 7) << 4);
            i32x4 v = *(const i32x4*)(ximg + g);
            *(i32x4*)(lds + d) = v;
        }
    }

    // epilogue constants hoisted before the K-loop
    float sc[2];
    int b2[2];
    const int coutbase = cq * 64 + chalf * 32;
#pragma unroll
    for (int j = 0; j < 2; ++j) {
        int cout = coutbase + j * 16 + row;
        sc[j] = wscale[cout] * 0.5f;          // 0.05/0.1 * ws
        b2[j] = 2 * bias[cout];
    }

    __syncthreads();

    // per-m center pixel index in halo (padded coords, rows 0..5 of halo)
    int pc[7];
#pragma unroll
    for (int m = 0; m < 7; ++m) {
        int off = pxhalf * 112 + m * 16 + row;               // 0..223
        int lr = (off >= 56) + (off >= 112) + (off >= 168);  // off/56
        int w = off - lr * 56;
        pc[m] = (lr + 1) * PH + (w + 1);
    }

    const int tapd[9] = {-PH - 1, -PH, -PH + 1, -1, 0, 1, PH - 1, PH, PH + 1};

    // B direct from global (fragment-ordered, L2-resident), 1-step prefetch.
    const signed char* wbase = wq + (size_t)(cq * 4 + chalf * 2) * 1024 + lane * 16;

    i32x4 acc[7][2] = {};
    i32x4 bn0 = *(const i32x4*)(wbase);
    i32x4 bn1 = *(const i32x4*)(wbase + 1024);

#pragma unroll
    for (int s = 0; s < 18; ++s) {
        const int t = s >> 1, kb = s & 1;
        i32x4 b0 = bn0, b1 = bn1;
        if (s < 17) {   // prefetch next step's B fragments (hidden under 14 MFMAs)
            bn0 = *(const i32x4*)(wbase + (s + 1) * 16384);
            bn1 = *(const i32x4*)(wbase + (s + 1) * 16384 + 1024);
        }
        // A ds_reads (swizzled)
        i32x4 a[7];
#pragma unroll
        for (int m = 0; m < 7; ++m) {
            int pix = pc[m] + tapd[t];
            int g = (pix << 7) + (kb << 6) + (grp << 4);
            int d = g ^ ((pix & 7) << 4);
            a[m] = *(const i32x4*)(lds + d);
        }
#pragma unroll
        for (int m = 0; m < 7; ++m) {
            acc[m][0] = __builtin_amdgcn_mfma_i32_16x16x64_i8(a[m], b0, acc[m][0], 0, 0, 0);
            acc[m][1] = __builtin_amdgcn_mfma_i32_16x16x64_i8(a[m], b1, acc[m][1], 0, 0, 0);
        }
    }

    // ---- epilogue: quantize -> LDS transpose -> contiguous NONTEMPORAL stores ----
    __syncthreads();                     // all waves done with A-LDS
    int* elds = (int*)lds;
    const int pixbase = rb * 224;
    const size_t nbase = (size_t)n * (COUT * PIX_PER_IMG);
#pragma unroll
    for (int p = 0; p < 2; ++p) {
        if (chalf == p) {
#pragma unroll
            for (int m = 0; m < 7; ++m) {
                int px0 = pxhalf * 112 + m * 16 + grp * 4;
#pragma unroll
                for (int j = 0; j < 2; ++j) {
                    int cl = j * 16 + row;
                    i32x4 v;
#pragma unroll
                    for (int r = 0; r < 4; ++r) {
                        int o = acc[m][j][r] + b2[j];
                        float f = fmaf((float)o, sc[j], 5.0f);
                        f = rintf(f);                 // RNE == jnp.round
                        f = fminf(fmaxf(f, -128.0f), 127.0f);
                        v[r] = (int)f;
                    }
                    *(i32x4*)(elds + cl * EP_STRIDE + px0) = v;
                }
            }
        }
        __syncthreads();
        // all 4 waves: read back rows, nontemporal-store contiguous 896B runs
#pragma unroll
        for (int rnd = 0; rnd < 7; ++rnd) {
            int tg = rnd * 256 + tid;          // 0..1791 = 32 couts x 56 quads
            int cl = tg / 56;
            int q = tg - cl * 56;
            i32x4 v = *(const i32x4*)(elds + cl * EP_STRIDE + q * 4);
            int cout = cq * 64 + p * 32 + cl;
            __builtin_nontemporal_store(v,
                (i32x4*)(out + nbase + (size_t)cout * PIX_PER_IMG + pixbase + q * 4));
        }
        __syncthreads();
    }
}

extern "C" void kernel_launch(void* const* d_in, const int* in_sizes, int n_in,
                              void* d_out, int out_size, void* d_ws, size_t ws_size,
                              hipStream_t stream) {
    const int* x = (const int*)d_in[0];
    const int* w = (const int*)d_in[1];
    const int* bias = (const int*)d_in[2];
    const float* ws = (const float*)d_in[3];
    int* out = (int*)d_out;

    signed char* xq = (signed char*)d_ws;                 // padded NHWC int8
    signed char* wq = xq + XQ_PAD_BYTES;                  // 288 KB fragment-ordered weights

    pack_x_kernel<<<NB_N * HH, 256, 0, stream>>>(x, xq);  // halo fused in
    pack_w_kernel<<<72, 256, 0, stream>>>(w, wq);
    conv_kernel<<<1792, 256, 0, stream>>>(xq, wq, bias, ws, out);
}